// Round 3
// baseline (126.961 us; speedup 1.0000x reference)
//
#include <hip/hip_runtime.h>
#include <hip/hip_bf16.h>

#define N_CLS 4096
#define FDIM  2048

typedef float  floatx4 __attribute__((ext_vector_type(4)));
typedef short  shortx8 __attribute__((ext_vector_type(8)));

__device__ __forceinline__ unsigned short f2bf(float x) {
    union { float f; unsigned int u; } v; v.f = x;
    unsigned int r = v.u + 0x7fffu + ((v.u >> 16) & 1u);
    return (unsigned short)(r >> 16);
}

// ---------------------------------------------------------------------------
// Kernel 0: zero the accumulator.
// ---------------------------------------------------------------------------
__global__ void zero_kernel(float* __restrict__ accum) { *accum = 0.0f; }

// ---------------------------------------------------------------------------
// Kernel A: per-row norm of prototypes, fp32 diag <p_i, w_i>, bf16 conversion
// of normalized prototypes and classifier weights into workspace.
// ---------------------------------------------------------------------------
__global__ __launch_bounds__(256) void prep_kernel(
    const float* __restrict__ bnd,
    const float* __restrict__ proto,
    const float* __restrict__ wgt,
    unsigned short* __restrict__ pbf,
    unsigned short* __restrict__ wbf,
    float* __restrict__ t1,
    float* __restrict__ cc)
{
    const int row = blockIdx.x;
    const int tid = threadIdx.x;
    const size_t base = (size_t)row * FDIM + (size_t)tid * 8;

    floatx4 p0 = *(const floatx4*)(proto + base);
    floatx4 p1 = *(const floatx4*)(proto + base + 4);
    floatx4 w0 = *(const floatx4*)(wgt + base);
    floatx4 w1 = *(const floatx4*)(wgt + base + 4);

    float ss = 0.f, dt = 0.f;
#pragma unroll
    for (int k = 0; k < 4; ++k) {
        ss += p0[k] * p0[k] + p1[k] * p1[k];
        dt += p0[k] * w0[k] + p1[k] * w1[k];
    }
#pragma unroll
    for (int off = 32; off > 0; off >>= 1) {
        ss += __shfl_down(ss, off);
        dt += __shfl_down(dt, off);
    }

    __shared__ float sss[4], sdt[4];
    __shared__ float srn;
    const int wid = tid >> 6, lane = tid & 63;
    if (lane == 0) { sss[wid] = ss; sdt[wid] = dt; }
    __syncthreads();
    if (tid == 0) {
        float SS = sss[0] + sss[1] + sss[2] + sss[3];
        float DT = sdt[0] + sdt[1] + sdt[2] + sdt[3];
        float rn = 1.0f / fmaxf(sqrtf(SS), 1e-12f);
        srn = rn;
        float bv = bnd[row];
        t1[row] = (1.0f - bv) * (DT * rn);  // (1-b_i) * diag_i  (fp32)
        cc[row] = bv - 1.0f;                // (b_j - 1)
    }
    __syncthreads();
    const float rn = srn;

    shortx8 pv, wv;
#pragma unroll
    for (int k = 0; k < 4; ++k) {
        pv[k]     = (short)f2bf(p0[k] * rn);
        pv[k + 4] = (short)f2bf(p1[k] * rn);
        wv[k]     = (short)f2bf(w0[k]);
        wv[k + 4] = (short)f2bf(w1[k]);
    }
    *(shortx8*)(pbf + base) = pv;
    *(shortx8*)(wbf + base) = wv;
}

// ---------------------------------------------------------------------------
// Kernel B: fused bf16 GEMM (s = P @ W^T) + relu(t1[i] + s*c[j]) off-diag sum.
// m97 structure: 128x128 tile, BK=64, 4 waves (2x2), each wave 64x64 output
// via 4x4 fragments of mfma_f32_16x16x32_bf16, global_load_lds width 16.
// ---------------------------------------------------------------------------
__global__ __launch_bounds__(256) void gemm_reduce_kernel(
    const unsigned short* __restrict__ A,   // p_bf16 [4096][2048]
    const unsigned short* __restrict__ B,   // w_bf16 [4096][2048]
    const float* __restrict__ t1,
    const float* __restrict__ cc,
    float* __restrict__ accum)
{
    __shared__ unsigned short lA[128 * 64];
    __shared__ unsigned short lB[128 * 64];
    __shared__ float red[4];

    const int tid  = threadIdx.x;
    const int wid  = tid >> 6;
    const int lane = tid & 63;

    // XCD-aware swizzle: 1024 blocks, 1024 % 8 == 0 -> bijective simple form.
    const int b = blockIdx.x;
    const int s = (b & 7) * 128 + (b >> 3);
    const int bi = s >> 5;   // consecutive s share the A panel (L2-resident)
    const int bj = s & 31;

    const int wm = wid >> 1, wn = wid & 1;
    const int lr  = lane & 15;
    const int lk8 = (lane >> 4) << 3;

    floatx4 acc[4][4];
#pragma unroll
    for (int m = 0; m < 4; ++m)
#pragma unroll
        for (int n = 0; n < 4; ++n) acc[m][n] = (floatx4)0.0f;

    const int arow0 = bi * 128;
    const int brow0 = bj * 128;
    const int srow  = wid * 32 + (lane >> 3);   // staging row (plus t*8)
    const int scol  = (lane & 7) << 3;          // staging col (8 bf16 = 16B)

    for (int kt = 0; kt < FDIM; kt += 64) {
#pragma unroll
        for (int t = 0; t < 4; ++t) {
            const unsigned short* gA =
                A + (size_t)(arow0 + srow + t * 8) * FDIM + kt + scol;
            __builtin_amdgcn_global_load_lds(
                (const __attribute__((address_space(1))) void*)gA,
                (__attribute__((address_space(3))) void*)&lA[(wid * 32 + t * 8) * 64],
                16, 0, 0);
        }
#pragma unroll
        for (int t = 0; t < 4; ++t) {
            const unsigned short* gB =
                B + (size_t)(brow0 + srow + t * 8) * FDIM + kt + scol;
            __builtin_amdgcn_global_load_lds(
                (const __attribute__((address_space(1))) void*)gB,
                (__attribute__((address_space(3))) void*)&lB[(wid * 32 + t * 8) * 64],
                16, 0, 0);
        }
        __syncthreads();  // compiler drains vmcnt before s_barrier

#pragma unroll
        for (int kk = 0; kk < 64; kk += 32) {
            shortx8 af[4], bf[4];
#pragma unroll
            for (int m = 0; m < 4; ++m)
                af[m] = *(const shortx8*)&lA[(wm * 64 + m * 16 + lr) * 64 + kk + lk8];
#pragma unroll
            for (int n = 0; n < 4; ++n)
                bf[n] = *(const shortx8*)&lB[(wn * 64 + n * 16 + lr) * 64 + kk + lk8];
#pragma unroll
            for (int m = 0; m < 4; ++m)
#pragma unroll
                for (int n = 0; n < 4; ++n)
                    acc[m][n] = __builtin_amdgcn_mfma_f32_16x16x32_bf16(
                        af[m], bf[n], acc[m][n], 0, 0, 0);
        }
        __syncthreads();
    }

    // Epilogue: val = relu(t1[i] + s_ij * c[j]), skip i == j, sum.
    // C/D layout: col = lane&15, row = (lane>>4)*4 + reg  [m89-verified]
    const int row0 = arow0 + wm * 64 + (lane >> 4) * 4;
    const int col0 = brow0 + wn * 64 + lr;

    float tv[4][4];
#pragma unroll
    for (int m = 0; m < 4; ++m)
#pragma unroll
        for (int r = 0; r < 4; ++r)
            tv[m][r] = t1[row0 + m * 16 + r];

    float local = 0.f;
#pragma unroll
    for (int n = 0; n < 4; ++n) {
        const int j = col0 + n * 16;
        const float cj = cc[j];
#pragma unroll
        for (int m = 0; m < 4; ++m) {
#pragma unroll
            for (int r = 0; r < 4; ++r) {
                const int i = row0 + m * 16 + r;
                float v = fmaxf(tv[m][r] + acc[m][n][r] * cj, 0.f);
                local += (i == j) ? 0.f : v;
            }
        }
    }

#pragma unroll
    for (int off = 32; off > 0; off >>= 1)
        local += __shfl_down(local, off);
    if (lane == 0) red[wid] = local;
    __syncthreads();
    if (tid == 0) atomicAdd(accum, red[0] + red[1] + red[2] + red[3]);
}

// ---------------------------------------------------------------------------
// Kernel C: finalize -> FLOAT32 scalar (reference output dtype is float32!)
// ---------------------------------------------------------------------------
__global__ void finalize_kernel(const float* __restrict__ accum,
                                float* __restrict__ out)
{
    const float denom = 4096.0f * 4095.0f;  // exact in fp32 (24-bit value)
    out[0] = *accum / denom;
}

extern "C" void kernel_launch(void* const* d_in, const int* in_sizes, int n_in,
                              void* d_out, int out_size, void* d_ws, size_t ws_size,
                              hipStream_t stream) {
    const float* bnd   = (const float*)d_in[0];
    const float* proto = (const float*)d_in[1];
    const float* wgt   = (const float*)d_in[2];

    char* ws = (char*)d_ws;
    unsigned short* pbf = (unsigned short*)ws;                              // 16 MB
    unsigned short* wbf = (unsigned short*)(ws + (size_t)N_CLS * FDIM * 2); // 16 MB
    float* t1    = (float*)(ws + (size_t)N_CLS * FDIM * 4);
    float* cc    = t1 + N_CLS;
    float* accum = cc + N_CLS;

    zero_kernel<<<1, 1, 0, stream>>>(accum);
    prep_kernel<<<N_CLS, 256, 0, stream>>>(bnd, proto, wgt, pbf, wbf, t1, cc);
    gemm_reduce_kernel<<<1024, 256, 0, stream>>>(pbf, wbf, t1, cc, accum);
    finalize_kernel<<<1, 1, 0, stream>>>(accum, (float*)d_out);
}

// Round 4
// 103.182 us; speedup vs baseline: 1.2305x; 1.2305x over previous
//
#include <hip/hip_runtime.h>
#include <hip/hip_bf16.h>

#define N_CLS 4096
#define FDIM  2048
#define NT    (FDIM / 64)   // 32 K-tiles of BK=64

typedef float  floatx4 __attribute__((ext_vector_type(4)));
typedef short  shortx8 __attribute__((ext_vector_type(8)));

__device__ __forceinline__ unsigned short f2bf(float x) {
    union { float f; unsigned int u; } v; v.f = x;
    unsigned int r = v.u + 0x7fffu + ((v.u >> 16) & 1u);
    return (unsigned short)(r >> 16);
}

// ---------------------------------------------------------------------------
// Kernel 0: zero the accumulator.
// ---------------------------------------------------------------------------
__global__ void zero_kernel(float* __restrict__ accum) { *accum = 0.0f; }

// ---------------------------------------------------------------------------
// Kernel A: per-row norm of prototypes, fp32 diag <p_i, w_i>, bf16 conversion
// of normalized prototypes and classifier weights into workspace.
// ---------------------------------------------------------------------------
__global__ __launch_bounds__(256) void prep_kernel(
    const float* __restrict__ bnd,
    const float* __restrict__ proto,
    const float* __restrict__ wgt,
    unsigned short* __restrict__ pbf,
    unsigned short* __restrict__ wbf,
    float* __restrict__ t1,
    float* __restrict__ cc)
{
    const int row = blockIdx.x;
    const int tid = threadIdx.x;
    const size_t base = (size_t)row * FDIM + (size_t)tid * 8;

    floatx4 p0 = *(const floatx4*)(proto + base);
    floatx4 p1 = *(const floatx4*)(proto + base + 4);
    floatx4 w0 = *(const floatx4*)(wgt + base);
    floatx4 w1 = *(const floatx4*)(wgt + base + 4);

    float ss = 0.f, dt = 0.f;
#pragma unroll
    for (int k = 0; k < 4; ++k) {
        ss += p0[k] * p0[k] + p1[k] * p1[k];
        dt += p0[k] * w0[k] + p1[k] * w1[k];
    }
#pragma unroll
    for (int off = 32; off > 0; off >>= 1) {
        ss += __shfl_down(ss, off);
        dt += __shfl_down(dt, off);
    }

    __shared__ float sss[4], sdt[4];
    __shared__ float srn;
    const int wid = tid >> 6, lane = tid & 63;
    if (lane == 0) { sss[wid] = ss; sdt[wid] = dt; }
    __syncthreads();
    if (tid == 0) {
        float SS = sss[0] + sss[1] + sss[2] + sss[3];
        float DT = sdt[0] + sdt[1] + sdt[2] + sdt[3];
        float rn = 1.0f / fmaxf(sqrtf(SS), 1e-12f);
        srn = rn;
        float bv = bnd[row];
        t1[row] = (1.0f - bv) * (DT * rn);  // (1-b_i) * diag_i  (fp32)
        cc[row] = bv - 1.0f;                // (b_j - 1)
    }
    __syncthreads();
    const float rn = srn;

    shortx8 pv, wv;
#pragma unroll
    for (int k = 0; k < 4; ++k) {
        pv[k]     = (short)f2bf(p0[k] * rn);
        pv[k + 4] = (short)f2bf(p1[k] * rn);
        wv[k]     = (short)f2bf(w0[k]);
        wv[k + 4] = (short)f2bf(w1[k]);
    }
    *(shortx8*)(pbf + base) = pv;
    *(shortx8*)(wbf + base) = wv;
}

// ---------------------------------------------------------------------------
// Kernel B: fused bf16 GEMM (s = P @ W^T) + relu(t1[i] + s*c[j]) off-diag sum.
// BM=256, BN=128, BK=64, 8 waves (4x2), 3 LDS buffers (prefetch distance 2),
// counted vmcnt(6) (never drained in main loop), st_16x32 LDS swizzle applied
// as pre-swizzled global source (global_load_lds linear dest) + swizzled
// ds_read. Two sub-phases per K-tile, raw s_barrier, setprio around MFMA.
//
// LDS per buffer: A = [2 colblk][256 rows][32 cols] bf16 (32 KB, swizzled:
// byte ^= ((row>>3)&1)<<5), B likewise with 128 rows (16 KB). 3 x 48 KB.
// ---------------------------------------------------------------------------
__global__ __launch_bounds__(512, 2) void gemm_reduce_kernel(
    const unsigned short* __restrict__ A,   // p_bf16 [4096][2048]
    const unsigned short* __restrict__ B,   // w_bf16 [4096][2048]
    const float* __restrict__ t1,
    const float* __restrict__ cc,
    float* __restrict__ accum)
{
    __shared__ unsigned short sAB[3][24576];   // 3 x (16384 A + 8192 B) shorts
    __shared__ float red[8];

    const int tid  = threadIdx.x;
    const int wid  = tid >> 6;
    const int lane = tid & 63;

    // XCD-aware block swizzle: 512 blocks -> each XCD gets an 8x8 sub-grid
    // of the 16(bi) x 32(bj) tile grid (A-panels and B-panels both L2-shared).
    const int b   = blockIdx.x;
    const int xcd = b & 7, sl = b >> 3;              // sl in 0..63
    const int bi  = ((xcd & 1) << 3) + (sl & 7);     // 0..15
    const int bj  = ((xcd >> 1) << 3) + (sl >> 3);   // 0..31
    const int arow0 = bi * 256;
    const int brow0 = bj * 128;

    const int wm = wid >> 1;   // 0..3 : wave's 64-row strip of A
    const int wn = wid & 1;    // 0..1 : wave's 64-col strip of B
    const int lr = lane & 15;
    // k-offset within a 32-col block for frag reads, with st_16x32 swizzle:
    const int lkk = (((lane >> 4) << 3)) ^ (((lane >> 3) & 1) << 4);

    // staging geometry: chunk = 1 KB = 16 rows x 32 cols (one colblk slice);
    // lane l writes LDS base+16B*l  ->  global row +(l>>2), cols swizzled.
    const int srow = lane >> 2;                                   // 0..15
    const int sgcol = (((lane & 3) << 3)) ^ (((lane >> 5) & 1) << 4);

    floatx4 acc[4][4];
#pragma unroll
    for (int m = 0; m < 4; ++m)
#pragma unroll
        for (int n = 0; n < 4; ++n) acc[m][n] = (floatx4)0.0f;

    // stage chunk (wid*6+j) of K-tile tt into buffer bnx
    auto stage = [&](int j, int tt, int bnx) {
        const int c = wid * 6 + j;          // 0..47 ; 0-31 = A, 32-47 = B
        const int ktt = tt << 6;
        if (c < 32) {
            const int colblk = c >> 4;
            const int row = ((c & 15) << 4) + srow;
            const unsigned short* src =
                A + (size_t)(arow0 + row) * FDIM + ktt + (colblk << 5) + sgcol;
            __builtin_amdgcn_global_load_lds(
                (const __attribute__((address_space(1))) void*)src,
                (__attribute__((address_space(3))) void*)&sAB[bnx][c << 9],
                16, 0, 0);
        } else {
            const int cb = c - 32;
            const int colblk = cb >> 3;
            const int row = ((cb & 7) << 4) + srow;
            const unsigned short* src =
                B + (size_t)(brow0 + row) * FDIM + ktt + (colblk << 5) + sgcol;
            __builtin_amdgcn_global_load_lds(
                (const __attribute__((address_space(1))) void*)src,
                (__attribute__((address_space(3))) void*)&sAB[bnx][16384 + (cb << 9)],
                16, 0, 0);
        }
    };

    // ---- prologue: stage tiles 0 and 1; wait tile 0 only (tile 1 in flight)
#pragma unroll
    for (int j = 0; j < 6; ++j) stage(j, 0, 0);
#pragma unroll
    for (int j = 0; j < 6; ++j) stage(j, 1, 1);
    asm volatile("s_waitcnt vmcnt(6)" ::: "memory");
    __builtin_amdgcn_s_barrier();
    __builtin_amdgcn_sched_barrier(0);

    int cur = 0;
#pragma unroll 1
    for (int t = 0; t < NT; ++t) {
        const int nxt2 = (cur + 2 >= 3) ? cur - 1 : cur + 2;   // (cur+2)%3
        const unsigned short* LA = &sAB[cur][0];
        const unsigned short* LB = &sAB[cur][16384];
        const bool pf = (t + 2 < NT);

        // ---------- sub-phase 0 : C-frags m=0,1 ----------
        if (pf) { stage(0, t + 2, nxt2); stage(1, t + 2, nxt2); stage(2, t + 2, nxt2); }
        shortx8 af0[2][2], bf[4][2];
#pragma unroll
        for (int mi = 0; mi < 2; ++mi)
#pragma unroll
            for (int kx = 0; kx < 2; ++kx)
                af0[mi][kx] = *(const shortx8*)
                    &LA[kx * 8192 + (wm * 64 + mi * 16 + lr) * 32 + lkk];
#pragma unroll
        for (int n = 0; n < 4; ++n)
#pragma unroll
            for (int kx = 0; kx < 2; ++kx)
                bf[n][kx] = *(const shortx8*)
                    &LB[kx * 4096 + (wn * 64 + n * 16 + lr) * 32 + lkk];
        __builtin_amdgcn_s_barrier();
        __builtin_amdgcn_s_setprio(1);
#pragma unroll
        for (int kx = 0; kx < 2; ++kx)
#pragma unroll
            for (int mi = 0; mi < 2; ++mi)
#pragma unroll
                for (int n = 0; n < 4; ++n)
                    acc[mi][n] = __builtin_amdgcn_mfma_f32_16x16x32_bf16(
                        af0[mi][kx], bf[n][kx], acc[mi][n], 0, 0, 0);
        __builtin_amdgcn_s_setprio(0);
        __builtin_amdgcn_s_barrier();

        // ---------- sub-phase 1 : C-frags m=2,3 (B frags reused from regs) --
        if (pf) { stage(3, t + 2, nxt2); stage(4, t + 2, nxt2); stage(5, t + 2, nxt2); }
        shortx8 af1[2][2];
#pragma unroll
        for (int mi = 0; mi < 2; ++mi)
#pragma unroll
            for (int kx = 0; kx < 2; ++kx)
                af1[mi][kx] = *(const shortx8*)
                    &LA[kx * 8192 + (wm * 64 + (2 + mi) * 16 + lr) * 32 + lkk];
        __builtin_amdgcn_s_barrier();
        __builtin_amdgcn_s_setprio(1);
#pragma unroll
        for (int kx = 0; kx < 2; ++kx)
#pragma unroll
            for (int mi = 0; mi < 2; ++mi)
#pragma unroll
                for (int n = 0; n < 4; ++n)
                    acc[2 + mi][n] = __builtin_amdgcn_mfma_f32_16x16x32_bf16(
                        af1[mi][kx], bf[n][kx], acc[2 + mi][n], 0, 0, 0);
        __builtin_amdgcn_s_setprio(0);

        // end-of-tile: ensure tile t+1 landed for next iteration; keep the
        // 6 loads of tile t+2 in flight (counted vmcnt, never 0 mid-loop).
        if (pf)                   asm volatile("s_waitcnt vmcnt(6)" ::: "memory");
        else if (t + 1 < NT)      asm volatile("s_waitcnt vmcnt(0)" ::: "memory");
        __builtin_amdgcn_s_barrier();
        __builtin_amdgcn_sched_barrier(0);
        cur = (cur + 1 >= 3) ? 0 : cur + 1;
    }

    // ---- epilogue: val = relu(t1[i] + s_ij*c[j]), skip i==j, global sum.
    // C/D layout: col = lane&15, row = (lane>>4)*4 + reg  [m89-verified]
    const int row0 = arow0 + wm * 64 + (lane >> 4) * 4;
    const int col0 = brow0 + wn * 64 + lr;

    float tv[4][4];
#pragma unroll
    for (int m = 0; m < 4; ++m)
#pragma unroll
        for (int r = 0; r < 4; ++r)
            tv[m][r] = t1[row0 + m * 16 + r];

    float local = 0.f;
#pragma unroll
    for (int n = 0; n < 4; ++n) {
        const int j = col0 + n * 16;
        const float cj = cc[j];
#pragma unroll
        for (int m = 0; m < 4; ++m) {
#pragma unroll
            for (int r = 0; r < 4; ++r) {
                const int i = row0 + m * 16 + r;
                float v = fmaxf(tv[m][r] + acc[m][n][r] * cj, 0.f);
                local += (i == j) ? 0.f : v;
            }
        }
    }

#pragma unroll
    for (int off = 32; off > 0; off >>= 1)
        local += __shfl_down(local, off);
    if (lane == 0) red[wid] = local;
    __syncthreads();
    if (tid == 0) {
        float s = 0.f;
#pragma unroll
        for (int w = 0; w < 8; ++w) s += red[w];
        atomicAdd(accum, s);
    }
}

// ---------------------------------------------------------------------------
// Kernel C: finalize -> float32 scalar
// ---------------------------------------------------------------------------
__global__ void finalize_kernel(const float* __restrict__ accum,
                                float* __restrict__ out)
{
    const float denom = 4096.0f * 4095.0f;  // exact in fp32
    out[0] = *accum / denom;
}

extern "C" void kernel_launch(void* const* d_in, const int* in_sizes, int n_in,
                              void* d_out, int out_size, void* d_ws, size_t ws_size,
                              hipStream_t stream) {
    const float* bnd   = (const float*)d_in[0];
    const float* proto = (const float*)d_in[1];
    const float* wgt   = (const float*)d_in[2];

    char* ws = (char*)d_ws;
    unsigned short* pbf = (unsigned short*)ws;                              // 16 MB
    unsigned short* wbf = (unsigned short*)(ws + (size_t)N_CLS * FDIM * 2); // 16 MB
    float* t1    = (float*)(ws + (size_t)N_CLS * FDIM * 4);
    float* cc    = t1 + N_CLS;
    float* accum = cc + N_CLS;

    zero_kernel<<<1, 1, 0, stream>>>(accum);
    prep_kernel<<<N_CLS, 256, 0, stream>>>(bnd, proto, wgt, pbf, wbf, t1, cc);
    gemm_reduce_kernel<<<512, 512, 0, stream>>>(pbf, wbf, t1, cc, accum);
    finalize_kernel<<<1, 1, 0, stream>>>(accum, (float*)d_out);
}